// Round 1
// baseline (118.241 us; speedup 1.0000x reference)
//
#include <hip/hip_runtime.h>
#include <hip/hip_bf16.h>
#include <cstddef>

#define EMB   256
#define TWOD  512
#define NREL  128
#define BATCH 4096
#define LOG_SQRT_2PI 0.9189385332046727f

// ---------------------------------------------------------------------------
// Kernel 1: per-(r,k) transform of (mu, sigma) -> (a, c) stored K-major in ws,
// plus per-relation constant  const_r = sum_k e[r,k] + 512*prior_r.
//   a = -0.5/sigma^2 ; c = mu/sigma^2 ; e = -0.5 mu^2/sigma^2 - log(sigma) - C
// ---------------------------------------------------------------------------
__global__ __launch_bounds__(512) void nb_prep(
    const float* __restrict__ mus, const float* __restrict__ sigmas,
    const float* __restrict__ priors,
    float* __restrict__ cst, float* __restrict__ aT, float* __restrict__ cT)
{
    const int r = blockIdx.x;     // 0..127
    const int k = threadIdx.x;    // 0..511
    const float mu = mus[r * TWOD + k];
    const float s  = sigmas[r * TWOD + k];
    const float inv2 = 1.0f / (s * s);
    const float a = -0.5f * inv2;
    const float c = mu * inv2;
    float e = -0.5f * mu * mu * inv2 - logf(s) - LOG_SQRT_2PI;

    aT[k * NREL + r] = a;   // K-major so main kernel stages contiguously
    cT[k * NREL + r] = c;

    #pragma unroll
    for (int off = 32; off >= 1; off >>= 1)
        e += __shfl_down(e, off, 64);
    if ((k & 63) == 0) unsafeAtomicAdd(&cst[r], e);
    if (k == 0)        unsafeAtomicAdd(&cst[r], priors[r] * (float)TWOD);
}

// ---------------------------------------------------------------------------
// Kernel 2: main bilinear accumulation.
//   out[b,r] += sum_{k in krange} (a[r,k]*x[b,k] + c[r,k]) * x[b,k]
// BM=64 batch rows x all 128 relations per block; K split 4 ways across
// blockIdx.y (grid 64x4 = 256 blocks, 256 thr = 4 waves each).
// Per-thread register tile: 8b x 4r  (LDS-BW vs VALU balanced).
// ---------------------------------------------------------------------------
#define BM     64
#define KC     32
#define KSPLIT 4
#define KRANGE (TWOD / KSPLIT)   // 128

__global__ __launch_bounds__(256) void nb_main(
    const float* __restrict__ sbjs, const float* __restrict__ objs,
    const float* __restrict__ cst, const float* __restrict__ aT,
    const float* __restrict__ cT, float* __restrict__ out)
{
    __shared__ float a_s[KC][NREL];
    __shared__ float c_s[KC][NREL];
    __shared__ float x_s[KC][BM + 4];   // +4 pad: 16B-aligned b128 reads, mild write conflicts

    const int tid  = threadIdx.x;
    const int rcol = tid & 31;          // relations 4*rcol .. +3
    const int brow = tid >> 5;          // batch rows 8*brow .. +7
    const int b0   = blockIdx.x * BM;
    const int kbase = blockIdx.y * KRANGE;

    float acc[8][4];
    #pragma unroll
    for (int i = 0; i < 8; i++)
        #pragma unroll
        for (int j = 0; j < 4; j++) acc[i][j] = 0.0f;

    for (int kc = 0; kc < KRANGE / KC; kc++) {
        const int k0 = kbase + kc * KC;

        // ---- stage a, c: contiguous float4 copy (K-major in ws) ----
        const float4* ga  = (const float4*)(aT + (size_t)k0 * NREL);
        const float4* gc  = (const float4*)(cT + (size_t)k0 * NREL);
        float4* as4 = (float4*)&a_s[0][0];
        float4* cs4 = (float4*)&c_s[0][0];
        #pragma unroll
        for (int i = 0; i < 4; i++) {       // KC*NREL/4 = 1024 float4 / 256 thr
            const int idx = tid + i * 256;
            as4[idx] = ga[idx];
            cs4[idx] = gc[idx];
        }

        // ---- stage x tile transposed: x_s[k][b] ----
        // chunk never straddles the sbjs/objs boundary (KC=32 | 256)
        const float* src = (k0 < EMB) ? sbjs : objs;
        const int kk = k0 & (EMB - 1);
        #pragma unroll
        for (int i = 0; i < 2; i++) {       // BM rows * 8 float4 = 512 / 256 thr
            const int idx = tid + i * 256;
            const int row = idx >> 3;       // 0..63
            const int kq  = idx & 7;        // float4 index within 32-col chunk
            const float4 v = *(const float4*)(src + (size_t)(b0 + row) * EMB + kk + kq * 4);
            x_s[4 * kq + 0][row] = v.x;
            x_s[4 * kq + 1][row] = v.y;
            x_s[4 * kq + 2][row] = v.z;
            x_s[4 * kq + 3][row] = v.w;
        }
        __syncthreads();

        // ---- main accumulation ----
        #pragma unroll 4
        for (int k = 0; k < KC; k++) {
            float av[4], cv[4], xv[8];
            *(float4*)av       = *(const float4*)&a_s[k][rcol * 4];
            *(float4*)cv       = *(const float4*)&c_s[k][rcol * 4];
            *(float4*)(xv)     = *(const float4*)&x_s[k][brow * 8];
            *(float4*)(xv + 4) = *(const float4*)&x_s[k][brow * 8 + 4];
            #pragma unroll
            for (int i = 0; i < 8; i++)
                #pragma unroll
                for (int j = 0; j < 4; j++) {
                    const float t = fmaf(av[j], xv[i], cv[j]);
                    acc[i][j] = fmaf(t, xv[i], acc[i][j]);
                }
        }
        __syncthreads();
    }

    // ---- epilogue: atomic merge of the K-split partials ----
    float cadd[4] = {0.f, 0.f, 0.f, 0.f};
    if (blockIdx.y == 0)
        *(float4*)cadd = *(const float4*)(cst + rcol * 4);
    #pragma unroll
    for (int i = 0; i < 8; i++) {
        float* o = out + (size_t)(b0 + brow * 8 + i) * NREL + rcol * 4;
        #pragma unroll
        for (int j = 0; j < 4; j++)
            unsafeAtomicAdd(o + j, acc[i][j] + cadd[j]);
    }
}

// ---------------------------------------------------------------------------
// Fallback (only if ws is too small): one thread per (b,r), direct evaluation.
// ---------------------------------------------------------------------------
__global__ __launch_bounds__(256) void nb_slow(
    const float* __restrict__ sbjs, const float* __restrict__ objs,
    const float* __restrict__ mus, const float* __restrict__ sigmas,
    const float* __restrict__ priors, float* __restrict__ out)
{
    const int idx = blockIdx.x * 256 + threadIdx.x;
    const int b = idx >> 7;
    const int r = idx & (NREL - 1);
    float acc = priors[r] * (float)TWOD;
    for (int k = 0; k < TWOD; k++) {
        const float x  = (k < EMB) ? sbjs[(size_t)b * EMB + k]
                                   : objs[(size_t)b * EMB + (k - EMB)];
        const float mu = mus[r * TWOD + k];
        const float s  = sigmas[r * TWOD + k];
        const float z  = (x - mu) / s;
        acc += -0.5f * z * z - logf(s) - LOG_SQRT_2PI;
    }
    out[idx] = acc;
}

extern "C" void kernel_launch(void* const* d_in, const int* in_sizes, int n_in,
                              void* d_out, int out_size, void* d_ws, size_t ws_size,
                              hipStream_t stream)
{
    const float* sbjs   = (const float*)d_in[0];
    const float* objs   = (const float*)d_in[1];
    const float* mus    = (const float*)d_in[2];
    const float* sigmas = (const float*)d_in[3];
    const float* priors = (const float*)d_in[4];
    float* out = (float*)d_out;

    const size_t need = (size_t)(NREL + 2 * TWOD * NREL) * sizeof(float);
    if (ws_size >= need) {
        float* cst = (float*)d_ws;
        float* aT  = cst + NREL;
        float* cT  = aT + TWOD * NREL;
        hipMemsetAsync(cst, 0, NREL * sizeof(float), stream);
        hipMemsetAsync(out, 0, (size_t)BATCH * NREL * sizeof(float), stream);
        nb_prep<<<NREL, TWOD, 0, stream>>>(mus, sigmas, priors, cst, aT, cT);
        nb_main<<<dim3(BATCH / BM, KSPLIT), 256, 0, stream>>>(sbjs, objs, cst, aT, cT, out);
    } else {
        nb_slow<<<(BATCH * NREL) / 256, 256, 0, stream>>>(sbjs, objs, mus, sigmas, priors, out);
    }
}

// Round 2
// 80.336 us; speedup vs baseline: 1.4718x; 1.4718x over previous
//
#include <hip/hip_runtime.h>
#include <hip/hip_bf16.h>
#include <cstddef>
#include <cstdint>

#define EMB   256
#define TWOD  512
#define NREL  128
#define BATCH 4096
#define LOG_SQRT_2PI 0.9189385332046727f

typedef __bf16 bf16x8 __attribute__((ext_vector_type(8)));
typedef float  f32x4  __attribute__((ext_vector_type(4)));

__device__ __forceinline__ unsigned short f2bf(float f) {
    unsigned u = __builtin_bit_cast(unsigned, f);
    u = (u + 0x7FFFu + ((u >> 16) & 1u)) >> 16;
    return (unsigned short)u;
}

// ---------------------------------------------------------------------------
// K1: (mu, sigma, prior) -> Wc, Wa bf16 in MFMA staging layout [k8][r][8],
// plus cst[r] = sum_k e[r,k] + 512*prior_r.   a=-0.5/s^2, c=mu/s^2,
// e = -0.5 mu^2/s^2 - log(s) - C.   One block per relation, no atomics.
// ---------------------------------------------------------------------------
__global__ __launch_bounds__(256) void nb_prep(
    const float* __restrict__ mus, const float* __restrict__ sigmas,
    const float* __restrict__ priors,
    unsigned short* __restrict__ Wc, unsigned short* __restrict__ Wa,
    float* __restrict__ cst)
{
    const int r = blockIdx.x;
    const int tid = threadIdx.x;
    float esum = 0.0f;
    #pragma unroll
    for (int i = 0; i < 2; i++) {
        const int k = tid + i * 256;
        const float mu = mus[r * TWOD + k];
        const float s  = sigmas[r * TWOD + k];
        const float inv2 = 1.0f / (s * s);
        const float a = -0.5f * inv2;
        const float c = mu * inv2;
        esum += -0.5f * mu * mu * inv2 - logf(s) - LOG_SQRT_2PI;
        const int idx = (k >> 3) * (NREL * 8) + r * 8 + (k & 7);
        Wc[idx] = f2bf(c);
        Wa[idx] = f2bf(a);
    }
    // block reduce esum
    __shared__ float red[4];
    #pragma unroll
    for (int off = 32; off >= 1; off >>= 1)
        esum += __shfl_down(esum, off, 64);
    if ((tid & 63) == 0) red[tid >> 6] = esum;
    __syncthreads();
    if (tid == 0)
        cst[r] = red[0] + red[1] + red[2] + red[3] + priors[r] * (float)TWOD;
}

// ---------------------------------------------------------------------------
// K2: bf16 MFMA GEMM.  out_partial[kb][b,r] = sum_{k in slab}
//        c[r,k]*x[b,k] + a[r,k]*x[b,k]^2
// Block tile: 64 b-rows x 128 r (full N), 64 real k per block (kb = K-split 8).
// Grid (64, 8) = 512 blocks, 256 thr (4 waves), one-shot LDS stage (~49 KB).
// Wave w computes the 64x32 strip r in [w*32, w*32+32).
// ---------------------------------------------------------------------------
#define BGM 64
#define KSPLIT 8
#define PART_STRIDE ((size_t)BATCH * NREL)   // floats per partial slab

__device__ __forceinline__ void gl_lds16(const void* g, void* l) {
    __builtin_amdgcn_global_load_lds(
        (const __attribute__((address_space(1))) unsigned int*)g,
        (__attribute__((address_space(3))) unsigned int*)l, 16, 0, 0);
}

__global__ __launch_bounds__(256) void nb_gemm(
    const float* __restrict__ sbjs, const float* __restrict__ objs,
    const unsigned short* __restrict__ Wc, const unsigned short* __restrict__ Wa,
    const float* __restrict__ cst, float* __restrict__ dst, int use_atomic)
{
    // x planes padded: plane stride 520 ushort (1040 B) -> conflict-free
    // writes (bank shift 4 per k8) and 16B-aligned b128 reads.
    __shared__ __align__(16) unsigned short sYx [8 * 520];
    __shared__ __align__(16) unsigned short sYx2[8 * 520];
    __shared__ __align__(16) unsigned short sWc [8 * NREL * 8];   // [k8][r][8]
    __shared__ __align__(16) unsigned short sWa [8 * NREL * 8];

    const int tid  = threadIdx.x;
    const int wv   = tid >> 6;
    const int lane = tid & 63;
    const int m16  = lane & 15;
    const int quad = lane >> 4;
    const int b0   = blockIdx.x * BGM;
    const int kb   = blockIdx.y;
    const int k0   = kb * 64;            // real-k base of this slab

    // ---- stage W slabs (16 KB each, contiguous) via global_load_lds ----
    const unsigned short* wcg = Wc + (size_t)kb * 8 * NREL * 8;
    const unsigned short* wag = Wa + (size_t)kb * 8 * NREL * 8;
    #pragma unroll
    for (int c = 0; c < 4; c++) {
        const int off = (wv * 4 + c) * 512 + lane * 8;   // ushort units, 16B/lane
        gl_lds16(wcg + off, &sWc[off]);
        gl_lds16(wag + off, &sWa[off]);
    }

    // ---- stage x: fp32 -> bf16 (x and x^2) into padded planes ----
    const float* xb = (k0 < EMB) ? (sbjs + k0) : (objs + (k0 - EMB));
    #pragma unroll
    for (int i = 0; i < 4; i++) {
        const int idx = tid + i * 256;       // 1024 float4 loads
        const int m   = idx >> 4;            // 0..63
        const int c4  = idx & 15;            // float4 col within 64-k slice
        const float4 v = *(const float4*)(xb + (size_t)(b0 + m) * EMB + c4 * 4);
        ushort4 px = { f2bf(v.x), f2bf(v.y), f2bf(v.z), f2bf(v.w) };
        ushort4 p2 = { f2bf(v.x * v.x), f2bf(v.y * v.y),
                       f2bf(v.z * v.z), f2bf(v.w * v.w) };
        const int yoff = (c4 >> 1) * 520 + m * 8 + (c4 & 1) * 4;  // 8B aligned
        *(ushort4*)(&sYx [yoff]) = px;
        *(ushort4*)(&sYx2[yoff]) = p2;
    }
    __syncthreads();

    // ---- MFMA: 4 m-tiles x 2 n-tiles x 2 k-steps x 2 (x, x^2) = 32 ----
    f32x4 acc[4][2];
    #pragma unroll
    for (int mt = 0; mt < 4; mt++)
        #pragma unroll
        for (int nt = 0; nt < 2; nt++) acc[mt][nt] = (f32x4)0.0f;

    #pragma unroll
    for (int ks = 0; ks < 2; ks++) {
        const int k8 = ks * 4 + quad;
        bf16x8 ax[4], ax2[4], bc[2], ba[2];
        #pragma unroll
        for (int mt = 0; mt < 4; mt++) {
            const int o = k8 * 520 + (mt * 16 + m16) * 8;
            ax [mt] = *(const bf16x8*)(&sYx [o]);
            ax2[mt] = *(const bf16x8*)(&sYx2[o]);
        }
        #pragma unroll
        for (int nt = 0; nt < 2; nt++) {
            const int r = wv * 32 + nt * 16 + m16;
            const int o = k8 * (NREL * 8) + r * 8;
            bc[nt] = *(const bf16x8*)(&sWc[o]);
            ba[nt] = *(const bf16x8*)(&sWa[o]);
        }
        #pragma unroll
        for (int mt = 0; mt < 4; mt++)
            #pragma unroll
            for (int nt = 0; nt < 2; nt++) {
                acc[mt][nt] = __builtin_amdgcn_mfma_f32_16x16x32_bf16(
                                  ax [mt], bc[nt], acc[mt][nt], 0, 0, 0);
                acc[mt][nt] = __builtin_amdgcn_mfma_f32_16x16x32_bf16(
                                  ax2[mt], ba[nt], acc[mt][nt], 0, 0, 0);
            }
    }

    // ---- epilogue: C layout col=lane&15, row=quad*4+reg ----
    if (use_atomic) {
        float* out = dst;
        #pragma unroll
        for (int mt = 0; mt < 4; mt++)
            #pragma unroll
            for (int nt = 0; nt < 2; nt++) {
                const int rr   = wv * 32 + nt * 16 + m16;
                const int brow = b0 + mt * 16 + quad * 4;
                const float ca = (kb == 0) ? cst[rr] : 0.0f;
                #pragma unroll
                for (int reg = 0; reg < 4; reg++)
                    unsafeAtomicAdd(out + (size_t)(brow + reg) * NREL + rr,
                                    acc[mt][nt][reg] + ca);
            }
    } else {
        float* pd = dst + (size_t)kb * PART_STRIDE;
        #pragma unroll
        for (int mt = 0; mt < 4; mt++)
            #pragma unroll
            for (int nt = 0; nt < 2; nt++) {
                const int rr   = wv * 32 + nt * 16 + m16;
                const int brow = b0 + mt * 16 + quad * 4;
                #pragma unroll
                for (int reg = 0; reg < 4; reg++)
                    pd[(size_t)(brow + reg) * NREL + rr] = acc[mt][nt][reg];
            }
    }
}

// ---------------------------------------------------------------------------
// K3: reduce 8 partials + cst -> out (float4 per thread).
// ---------------------------------------------------------------------------
__global__ __launch_bounds__(256) void nb_reduce(
    const float* __restrict__ partial, const float* __restrict__ cst,
    float* __restrict__ out)
{
    const int idx4 = blockIdx.x * 256 + threadIdx.x;   // 0..131071
    const float4* p4 = (const float4*)partial;
    float4 s = p4[idx4];
    #pragma unroll
    for (int kb = 1; kb < KSPLIT; kb++) {
        const float4 v = p4[(size_t)kb * (PART_STRIDE / 4) + idx4];
        s.x += v.x; s.y += v.y; s.z += v.z; s.w += v.w;
    }
    const float4 cv = ((const float4*)cst)[idx4 & 31];
    s.x += cv.x; s.y += cv.y; s.z += cv.z; s.w += cv.w;
    ((float4*)out)[idx4] = s;
}

// ---------------------------------------------------------------------------
// Fallback: one thread per (b,r), direct fp32 evaluation.
// ---------------------------------------------------------------------------
__global__ __launch_bounds__(256) void nb_slow(
    const float* __restrict__ sbjs, const float* __restrict__ objs,
    const float* __restrict__ mus, const float* __restrict__ sigmas,
    const float* __restrict__ priors, float* __restrict__ out)
{
    const int idx = blockIdx.x * 256 + threadIdx.x;
    const int b = idx >> 7;
    const int r = idx & (NREL - 1);
    float acc = priors[r] * (float)TWOD;
    for (int k = 0; k < TWOD; k++) {
        const float x  = (k < EMB) ? sbjs[(size_t)b * EMB + k]
                                   : objs[(size_t)b * EMB + (k - EMB)];
        const float mu = mus[r * TWOD + k];
        const float s  = sigmas[r * TWOD + k];
        const float z  = (x - mu) / s;
        acc += -0.5f * z * z - logf(s) - LOG_SQRT_2PI;
    }
    out[idx] = acc;
}

extern "C" void kernel_launch(void* const* d_in, const int* in_sizes, int n_in,
                              void* d_out, int out_size, void* d_ws, size_t ws_size,
                              hipStream_t stream)
{
    const float* sbjs   = (const float*)d_in[0];
    const float* objs   = (const float*)d_in[1];
    const float* mus    = (const float*)d_in[2];
    const float* sigmas = (const float*)d_in[3];
    const float* priors = (const float*)d_in[4];
    float* out = (float*)d_out;

    char* ws = (char*)d_ws;
    const size_t o_wc  = 0;
    const size_t o_wa  = 128 << 10;
    const size_t o_cst = 256 << 10;
    const size_t o_par = (256 << 10) + 4096;
    const size_t need_par = o_par + (size_t)KSPLIT * PART_STRIDE * sizeof(float);
    const size_t need_at  = o_par;

    if (ws_size >= need_at) {
        unsigned short* Wc = (unsigned short*)(ws + o_wc);
        unsigned short* Wa = (unsigned short*)(ws + o_wa);
        float* cst = (float*)(ws + o_cst);
        nb_prep<<<NREL, 256, 0, stream>>>(mus, sigmas, priors, Wc, Wa, cst);
        if (ws_size >= need_par) {
            float* partial = (float*)(ws + o_par);
            nb_gemm<<<dim3(BATCH / BGM, KSPLIT), 256, 0, stream>>>(
                sbjs, objs, Wc, Wa, cst, partial, 0);
            nb_reduce<<<(BATCH * NREL / 4) / 256, 256, 0, stream>>>(partial, cst, out);
        } else {
            hipMemsetAsync(out, 0, (size_t)BATCH * NREL * sizeof(float), stream);
            nb_gemm<<<dim3(BATCH / BGM, KSPLIT), 256, 0, stream>>>(
                sbjs, objs, Wc, Wa, cst, out, 1);
        }
    } else {
        nb_slow<<<(BATCH * NREL) / 256, 256, 0, stream>>>(
            sbjs, objs, mus, sigmas, priors, out);
    }
}

// Round 3
// 73.471 us; speedup vs baseline: 1.6093x; 1.0934x over previous
//
#include <hip/hip_runtime.h>
#include <hip/hip_bf16.h>
#include <cstddef>
#include <cstdint>

#define EMB   256
#define TWOD  512
#define NREL  128
#define BATCH 4096
#define LOG_SQRT_2PI 0.9189385332046727f

typedef __bf16          bf16x8  __attribute__((ext_vector_type(8)));
typedef unsigned short  u16x8   __attribute__((ext_vector_type(8)));
typedef float           f32x4   __attribute__((ext_vector_type(4)));

__device__ __forceinline__ unsigned short f2bf(float f) {
    unsigned u = __builtin_bit_cast(unsigned, f);
    u = (u + 0x7FFFu + ((u >> 16) & 1u)) >> 16;
    return (unsigned short)u;
}

__device__ __forceinline__ bf16x8 pack8(float4 a, float4 b) {
    u16x8 u;
    u[0] = f2bf(a.x); u[1] = f2bf(a.y); u[2] = f2bf(a.z); u[3] = f2bf(a.w);
    u[4] = f2bf(b.x); u[5] = f2bf(b.y); u[6] = f2bf(b.z); u[7] = f2bf(b.w);
    return __builtin_bit_cast(bf16x8, u);
}

__device__ __forceinline__ void gl_lds16(const void* g, void* l) {
    __builtin_amdgcn_global_load_lds(
        (const __attribute__((address_space(1))) unsigned int*)g,
        (__attribute__((address_space(3))) unsigned int*)l, 16, 0, 0);
}

// ---------------------------------------------------------------------------
// K1: (mu, sigma, prior) -> Wc, Wa bf16 in MFMA B-layout [k8][r][8],
// plus cst[r] = sum_k e[r,k] + 512*prior_r.
//   a = -0.5/s^2 ; c = mu/s^2 ; e = -0.5 mu^2/s^2 - log s - C
// ---------------------------------------------------------------------------
__global__ __launch_bounds__(256) void nb_prep(
    const float* __restrict__ mus, const float* __restrict__ sigmas,
    const float* __restrict__ priors,
    unsigned short* __restrict__ Wc, unsigned short* __restrict__ Wa,
    float* __restrict__ cst)
{
    const int r = blockIdx.x;
    const int tid = threadIdx.x;
    float esum = 0.0f;
    #pragma unroll
    for (int i = 0; i < 2; i++) {
        const int k = tid + i * 256;
        const float mu = mus[r * TWOD + k];
        const float s  = sigmas[r * TWOD + k];
        const float inv2 = 1.0f / (s * s);
        esum += -0.5f * mu * mu * inv2 - logf(s) - LOG_SQRT_2PI;
        const int idx = (k >> 3) * (NREL * 8) + r * 8 + (k & 7);
        Wc[idx] = f2bf(mu * inv2);
        Wa[idx] = f2bf(-0.5f * inv2);
    }
    __shared__ float red[4];
    #pragma unroll
    for (int off = 32; off >= 1; off >>= 1)
        esum += __shfl_down(esum, off, 64);
    if ((tid & 63) == 0) red[tid >> 6] = esum;
    __syncthreads();
    if (tid == 0)
        cst[r] = red[0] + red[1] + red[2] + red[3] + priors[r] * (float)TWOD;
}

// ---------------------------------------------------------------------------
// K2: fully fused MFMA kernel.
//   out[b,r] = sum_k c[r,k]*x[b,k] + a[r,k]*x[b,k]^2 + cst[r]
// Grid 256 blocks (1/CU), 4 waves. BM=16 rows, full N=128, full K.
// A-frags (x, x^2) preloaded to registers (1 wave/SIMD -> ~512 VGPR budget).
// W streamed dbuf via global_load_lds, 8 chunks x 32 KB, LDS = 64 KB exact.
// ---------------------------------------------------------------------------
#define CHP  8                    // k8-planes per chunk per tensor
#define NCHK 8                    // chunks (64 k8-planes total)

__device__ __forceinline__ void issue_chunk(
    unsigned short* sW, const unsigned short* Wc, const unsigned short* Wa,
    int wv, int lane, int ch, int buf)
{
    const int t = wv & 1;
    const unsigned short* g = t ? Wa : Wc;
    const int pbase = (wv >> 1) * 4;
    #pragma unroll
    for (int j = 0; j < 4; j++) {
        #pragma unroll
        for (int h = 0; h < 2; h++) {
            const int p    = pbase + j;
            const int goff = (ch * CHP + p) * 1024 + h * 512 + lane * 8;
            const int loff = buf * 16384 + t * 8192 + p * 1024 + h * 512;
            gl_lds16(g + goff, &sW[loff]);   // lds dest: uniform base + lane*16B
        }
    }
}

__global__ __launch_bounds__(256, 1) void nb_fused(
    const float* __restrict__ sbjs, const float* __restrict__ objs,
    const unsigned short* __restrict__ Wc, const unsigned short* __restrict__ Wa,
    const float* __restrict__ cst, float* __restrict__ out)
{
    __shared__ unsigned short sW[2 * 2 * CHP * 1024];   // [buf][t][p][1024] 64 KB

    const int tid  = threadIdx.x;
    const int wv   = tid >> 6;
    const int lane = tid & 63;
    const int m16  = lane & 15;
    const int quad = lane >> 4;
    const int b0   = blockIdx.x * 16;

    issue_chunk(sW, Wc, Wa, wv, lane, 0, 0);

    // ---- prologue: preload all A-frags (x and x^2) into registers ----
    bf16x8 ax[16], ax2[16];
    {
        const int row = b0 + m16;
        #pragma unroll
        for (int fi = 0; fi < 16; fi++) {
            const int col = fi * 32 + quad * 8;          // compile-time branch per fi
            const float* p = (col < EMB)
                ? (sbjs + (size_t)row * EMB + col)
                : (objs + (size_t)row * EMB + (col - EMB));
            const float4 v0 = *(const float4*)p;
            const float4 v1 = *(const float4*)(p + 4);
            ax[fi] = pack8(v0, v1);
            const float4 s0 = {v0.x * v0.x, v0.y * v0.y, v0.z * v0.z, v0.w * v0.w};
            const float4 s1 = {v1.x * v1.x, v1.y * v1.y, v1.z * v1.z, v1.w * v1.w};
            ax2[fi] = pack8(s0, s1);
        }
    }

    f32x4 acc[2];
    acc[0] = (f32x4)0.0f;
    acc[1] = (f32x4)0.0f;

    __syncthreads();   // chunk 0 DMA complete (vmcnt drain) for all waves

    #pragma unroll
    for (int ch = 0; ch < NCHK; ch++) {
        const int buf = ch & 1;
        if (ch + 1 < NCHK)
            issue_chunk(sW, Wc, Wa, wv, lane, ch + 1, buf ^ 1);

        #pragma unroll
        for (int ks2 = 0; ks2 < 2; ks2++) {
            const int fi = ch * 2 + ks2;                 // compile-time (full unroll)
            const int pb = buf * 16384 + (ks2 * 4 + quad) * 1024;
            #pragma unroll
            for (int nt = 0; nt < 2; nt++) {
                const int r  = wv * 32 + nt * 16 + m16;
                const bf16x8 bc = *(const bf16x8*)&sW[pb + r * 8];
                const bf16x8 ba = *(const bf16x8*)&sW[pb + 8192 + r * 8];
                acc[nt] = __builtin_amdgcn_mfma_f32_16x16x32_bf16(
                              ax[fi],  bc, acc[nt], 0, 0, 0);
                acc[nt] = __builtin_amdgcn_mfma_f32_16x16x32_bf16(
                              ax2[fi], ba, acc[nt], 0, 0, 0);
            }
        }
        __syncthreads();   // protects buf reuse; drains next chunk's DMA
    }

    // ---- epilogue: C layout col(r)=lane&15, row(b)=quad*4+reg ----
    #pragma unroll
    for (int nt = 0; nt < 2; nt++) {
        const int r = wv * 32 + nt * 16 + m16;
        const float ca = cst[r];
        #pragma unroll
        for (int reg = 0; reg < 4; reg++)
            out[(size_t)(b0 + quad * 4 + reg) * NREL + r] = acc[nt][reg] + ca;
    }
}

// ---------------------------------------------------------------------------
// Fallback: one thread per (b,r), direct fp32 evaluation.
// ---------------------------------------------------------------------------
__global__ __launch_bounds__(256) void nb_slow(
    const float* __restrict__ sbjs, const float* __restrict__ objs,
    const float* __restrict__ mus, const float* __restrict__ sigmas,
    const float* __restrict__ priors, float* __restrict__ out)
{
    const int idx = blockIdx.x * 256 + threadIdx.x;
    const int b = idx >> 7;
    const int r = idx & (NREL - 1);
    float acc = priors[r] * (float)TWOD;
    for (int k = 0; k < TWOD; k++) {
        const float x  = (k < EMB) ? sbjs[(size_t)b * EMB + k]
                                   : objs[(size_t)b * EMB + (k - EMB)];
        const float mu = mus[r * TWOD + k];
        const float s  = sigmas[r * TWOD + k];
        const float z  = (x - mu) / s;
        acc += -0.5f * z * z - logf(s) - LOG_SQRT_2PI;
    }
    out[idx] = acc;
}

extern "C" void kernel_launch(void* const* d_in, const int* in_sizes, int n_in,
                              void* d_out, int out_size, void* d_ws, size_t ws_size,
                              hipStream_t stream)
{
    const float* sbjs   = (const float*)d_in[0];
    const float* objs   = (const float*)d_in[1];
    const float* mus    = (const float*)d_in[2];
    const float* sigmas = (const float*)d_in[3];
    const float* priors = (const float*)d_in[4];
    float* out = (float*)d_out;

    char* ws = (char*)d_ws;
    const size_t o_wc  = 0;                        // 128 KB
    const size_t o_wa  = 256 << 10;                // 128 KB (generous spacing)
    const size_t o_cst = 512 << 10;                // 512 B
    const size_t need  = o_cst + NREL * sizeof(float);

    if (ws_size >= need) {
        unsigned short* Wcp = (unsigned short*)(ws + o_wc);
        unsigned short* Wap = (unsigned short*)(ws + o_wa);
        float* cst = (float*)(ws + o_cst);
        nb_prep<<<NREL, 256, 0, stream>>>(mus, sigmas, priors, Wcp, Wap, cst);
        nb_fused<<<BATCH / 16, 256, 0, stream>>>(sbjs, objs, Wcp, Wap, cst, out);
    } else {
        nb_slow<<<(BATCH * NREL) / 256, 256, 0, stream>>>(
            sbjs, objs, mus, sigmas, priors, out);
    }
}

// Round 4
// 72.436 us; speedup vs baseline: 1.6323x; 1.0143x over previous
//
#include <hip/hip_runtime.h>
#include <hip/hip_bf16.h>
#include <cstddef>
#include <cstdint>

#define EMB   256
#define TWOD  512
#define NREL  128
#define BATCH 4096
#define LOG_SQRT_2PI 0.9189385332046727f

typedef __bf16          bf16x8  __attribute__((ext_vector_type(8)));
typedef unsigned short  u16x8   __attribute__((ext_vector_type(8)));
typedef float           f32x4   __attribute__((ext_vector_type(4)));

__device__ __forceinline__ unsigned short f2bf(float f) {
    unsigned u = __builtin_bit_cast(unsigned, f);
    u = (u + 0x7FFFu + ((u >> 16) & 1u)) >> 16;
    return (unsigned short)u;
}

__device__ __forceinline__ bf16x8 pack8(float4 a, float4 b) {
    u16x8 u;
    u[0] = f2bf(a.x); u[1] = f2bf(a.y); u[2] = f2bf(a.z); u[3] = f2bf(a.w);
    u[4] = f2bf(b.x); u[5] = f2bf(b.y); u[6] = f2bf(b.z); u[7] = f2bf(b.w);
    return __builtin_bit_cast(bf16x8, u);
}

// ---------------------------------------------------------------------------
// K1: (mu, sigma, prior) -> Wi bf16 interleaved [k8][r][c:8 | a:8] (256 KB),
// cst[r] = sum_k e + 512*prior.  Grid 128 blocks x 64 thr (1 wave), one
// k8-oct per thread: 32 B contiguous store, wave-reduce for cst, no LDS.
// ---------------------------------------------------------------------------
__global__ __launch_bounds__(64) void nb_prep(
    const float* __restrict__ mus, const float* __restrict__ sigmas,
    const float* __restrict__ priors,
    unsigned short* __restrict__ Wi, float* __restrict__ cst)
{
    const int r  = blockIdx.x;
    const int k8 = threadIdx.x;          // 0..63
    const float* mp = mus    + (size_t)r * TWOD + k8 * 8;
    const float* sp = sigmas + (size_t)r * TWOD + k8 * 8;
    const float4 m0 = *(const float4*)mp,       m1 = *(const float4*)(mp + 4);
    const float4 s0 = *(const float4*)sp,       s1 = *(const float4*)(sp + 4);

    float mu[8] = {m0.x, m0.y, m0.z, m0.w, m1.x, m1.y, m1.z, m1.w};
    float sg[8] = {s0.x, s0.y, s0.z, s0.w, s1.x, s1.y, s1.z, s1.w};

    u16x8 pc, pa;
    float esum = 0.0f;
    #pragma unroll
    for (int i = 0; i < 8; i++) {
        const float inv2 = 1.0f / (sg[i] * sg[i]);
        pc[i] = f2bf(mu[i] * inv2);
        pa[i] = f2bf(-0.5f * inv2);
        esum += -0.5f * mu[i] * mu[i] * inv2 - __logf(sg[i]) - LOG_SQRT_2PI;
    }
    unsigned short* w = Wi + (size_t)k8 * (NREL * 16) + r * 16;
    *(u16x8*)w       = pc;
    *(u16x8*)(w + 8) = pa;

    #pragma unroll
    for (int off = 32; off >= 1; off >>= 1)
        esum += __shfl_down(esum, off, 64);
    if (k8 == 0) cst[r] = esum + priors[r] * (float)TWOD;
}

// ---------------------------------------------------------------------------
// K2: barrier-free, LDS-free fused MFMA kernel.
//   out[b,r] = sum_k c[r,k]*x[b,k] + a[r,k]*x[b,k]^2 + cst[r]
// Grid 256 blocks (1/CU), 4 waves, BM=16 rows, full K. Each wave owns the
// 32-relation strip [wv*32, wv*32+32): its B-frags are private -> no LDS, no
// __syncthreads anywhere. B-frags load global->VGPR (16B/lane contiguous,
// 256x L2 reuse); compiler free to software-pipeline loads vs MFMA with
// fine-grained vmcnt. A-frags (x, x^2) preloaded to registers (1 wave/SIMD).
// Four independent acc chains (c/a x 2 n-strips).
// ---------------------------------------------------------------------------
__global__ __launch_bounds__(256, 1) void nb_fused(
    const float* __restrict__ sbjs, const float* __restrict__ objs,
    const unsigned short* __restrict__ Wi,
    const float* __restrict__ cst, float* __restrict__ out)
{
    const int tid  = threadIdx.x;
    const int wv   = tid >> 6;
    const int lane = tid & 63;
    const int m16  = lane & 15;
    const int quad = lane >> 4;
    const int b0   = blockIdx.x * 16;
    const int row  = b0 + m16;

    // ---- preload all A-frags: x and x^2, bf16-packed ----
    bf16x8 ax[16], ax2[16];
    #pragma unroll
    for (int fi = 0; fi < 16; fi++) {
        const int col = fi * 32 + quad * 8;          // compile-time per fi
        const float* p = (col < EMB)
            ? (sbjs + (size_t)row * EMB + col)
            : (objs + (size_t)row * EMB + (col - EMB));
        const float4 v0 = *(const float4*)p;
        const float4 v1 = *(const float4*)(p + 4);
        ax[fi] = pack8(v0, v1);
        const float4 q0 = {v0.x * v0.x, v0.y * v0.y, v0.z * v0.z, v0.w * v0.w};
        const float4 q1 = {v1.x * v1.x, v1.y * v1.y, v1.z * v1.z, v1.w * v1.w};
        ax2[fi] = pack8(q0, q1);
    }

    f32x4 accc[2], acca[2];
    accc[0] = (f32x4)0.0f; accc[1] = (f32x4)0.0f;
    acca[0] = (f32x4)0.0f; acca[1] = (f32x4)0.0f;

    // ---- K loop: 16 frags x (2 strips x 2 tensors) MFMA, no barriers ----
    // B-frag for (fi, strip nt): plane k8 = fi*4+quad, r = wv*32+nt*16+m16,
    // addr = k8*4096B + r*32B  (c at +0, a at +16B), 16B/lane contiguous.
    const unsigned short* wbase = Wi + (size_t)quad * (NREL * 16)
                                     + (wv * 32 + m16) * 16;
    #pragma unroll
    for (int fi = 0; fi < 16; fi++) {
        const unsigned short* wp = wbase + (size_t)fi * 4 * (NREL * 16);
        const bf16x8 bc0 = *(const bf16x8*)(wp);
        const bf16x8 ba0 = *(const bf16x8*)(wp + 8);
        const bf16x8 bc1 = *(const bf16x8*)(wp + 256);   // nt=1: +16 r
        const bf16x8 ba1 = *(const bf16x8*)(wp + 264);
        accc[0] = __builtin_amdgcn_mfma_f32_16x16x32_bf16(ax [fi], bc0, accc[0], 0, 0, 0);
        acca[0] = __builtin_amdgcn_mfma_f32_16x16x32_bf16(ax2[fi], ba0, acca[0], 0, 0, 0);
        accc[1] = __builtin_amdgcn_mfma_f32_16x16x32_bf16(ax [fi], bc1, accc[1], 0, 0, 0);
        acca[1] = __builtin_amdgcn_mfma_f32_16x16x32_bf16(ax2[fi], ba1, acca[1], 0, 0, 0);
    }

    // ---- epilogue: C layout col(r)=lane&15, row(b)=quad*4+reg ----
    #pragma unroll
    for (int nt = 0; nt < 2; nt++) {
        const int r = wv * 32 + nt * 16 + m16;
        const float ca = cst[r];
        #pragma unroll
        for (int reg = 0; reg < 4; reg++)
            out[(size_t)(b0 + quad * 4 + reg) * NREL + r] =
                accc[nt][reg] + acca[nt][reg] + ca;
    }
}

// ---------------------------------------------------------------------------
// Fallback: one thread per (b,r), direct fp32 evaluation.
// ---------------------------------------------------------------------------
__global__ __launch_bounds__(256) void nb_slow(
    const float* __restrict__ sbjs, const float* __restrict__ objs,
    const float* __restrict__ mus, const float* __restrict__ sigmas,
    const float* __restrict__ priors, float* __restrict__ out)
{
    const int idx = blockIdx.x * 256 + threadIdx.x;
    const int b = idx >> 7;
    const int r = idx & (NREL - 1);
    float acc = priors[r] * (float)TWOD;
    for (int k = 0; k < TWOD; k++) {
        const float x  = (k < EMB) ? sbjs[(size_t)b * EMB + k]
                                   : objs[(size_t)b * EMB + (k - EMB)];
        const float mu = mus[r * TWOD + k];
        const float s  = sigmas[r * TWOD + k];
        const float z  = (x - mu) / s;
        acc += -0.5f * z * z - logf(s) - LOG_SQRT_2PI;
    }
    out[idx] = acc;
}

extern "C" void kernel_launch(void* const* d_in, const int* in_sizes, int n_in,
                              void* d_out, int out_size, void* d_ws, size_t ws_size,
                              hipStream_t stream)
{
    const float* sbjs   = (const float*)d_in[0];
    const float* objs   = (const float*)d_in[1];
    const float* mus    = (const float*)d_in[2];
    const float* sigmas = (const float*)d_in[3];
    const float* priors = (const float*)d_in[4];
    float* out = (float*)d_out;

    char* ws = (char*)d_ws;
    const size_t o_w   = 0;                          // 256 KB interleaved W
    const size_t o_cst = 256 << 10;
    const size_t need  = o_cst + NREL * sizeof(float);

    if (ws_size >= need) {
        unsigned short* Wi = (unsigned short*)(ws + o_w);
        float* cst = (float*)(ws + o_cst);
        nb_prep<<<NREL, 64, 0, stream>>>(mus, sigmas, priors, Wi, cst);
        nb_fused<<<BATCH / 16, 256, 0, stream>>>(sbjs, objs, Wi, cst, out);
    } else {
        nb_slow<<<(BATCH * NREL) / 256, 256, 0, stream>>>(
            sbjs, objs, mus, sigmas, priors, out);
    }
}